// Round 1
// baseline (449.873 us; speedup 1.0000x reference)
//
#include <hip/hip_runtime.h>

// Problem constants
#define B_   32
#define CIN  256
#define H_   64
#define W_   64
#define COUT 512
#define G_   9
#define CPG_IN  28   // 252 used input channels / 9 groups
#define HW_  (H_*W_)         // 4096
#define HW4_ (HW_/4)         // 1024 float4 per plane

// ---------------------------------------------------------------------------
// Kernel A: v[o][g] = sum of w_pw[o, c] over group g's columns.
// g = c/56 for c < 504; c in [504,512) maps to centre group 4.
// ---------------------------------------------------------------------------
__global__ void reduce_w_kernel(const float* __restrict__ w, float* __restrict__ v) {
    __shared__ float vb[G_];
    const int o = blockIdx.x;
    const int t = threadIdx.x;    // 64 threads
    if (t < G_) vb[t] = 0.0f;
    __syncthreads();
    for (int c = t; c < COUT; c += 64) {
        int g = (c < 504) ? (c / 56) : 4;
        atomicAdd(&vb[g], w[o * COUT + c]);
    }
    __syncthreads();
    if (t < G_) v[o * G_ + t] = vb[t];
}

// ---------------------------------------------------------------------------
// Kernel B: s[b][g][h][w] = sum_{k<28} x[b][28g+k][h][w]   (float4 along w)
// ---------------------------------------------------------------------------
__global__ void group_sum_kernel(const float* __restrict__ x, float* __restrict__ s) {
    const int idx = blockIdx.x * 256 + threadIdx.x;   // float4 units; total B*9*1024
    const int hw = idx & (HW4_ - 1);
    const int gb = idx >> 10;          // b*9 + g
    const int g  = gb % G_;
    const int b  = gb / G_;
    const float4* xp = (const float4*)x;
    long base = ((long)(b * CIN + g * CPG_IN)) * HW4_ + hw;
    float4 acc = make_float4(0.f, 0.f, 0.f, 0.f);
#pragma unroll
    for (int k = 0; k < CPG_IN; ++k) {
        float4 t = xp[base + (long)k * HW4_];
        acc.x += t.x; acc.y += t.y; acc.z += t.z; acc.w += t.w;
    }
    ((float4*)s)[idx] = acc;
}

// ---------------------------------------------------------------------------
// Kernel C: out[b][o][h][w] = sum_g v[o][g] * s[b][g][h + g/3 - 1][w + g%3 - 1]
// Block: 256 threads -> tile of O_TILE=16 outputs x H_TILE=16 rows x 64 cols.
// s region for (b, h-tile) staged in LDS: [9][18][66] padded-with-zeros.
// ---------------------------------------------------------------------------
#define O_TILE 16
#define H_TILE 16
#define SROWS  (H_TILE + 2)   // 18
#define SCOLS  (W_ + 2)       // 66

__global__ __launch_bounds__(256) void shift_pw_kernel(const float* __restrict__ s,
                                                       const float* __restrict__ v,
                                                       float* __restrict__ out) {
    __shared__ float sl[G_][SROWS][SCOLS];   // 9*18*66*4 = 42768 B
    __shared__ float vt[O_TILE][G_];

    const int bid = blockIdx.x;
    const int ot  = bid & 31;         // 32 o-tiles
    const int ht  = (bid >> 5) & 3;   // 4 h-tiles
    const int b   = bid >> 7;         // 32 batches
    const int h0  = ht * H_TILE;
    const int tid = threadIdx.x;

    // load v tile (144 values)
    if (tid < O_TILE * G_) {
        int oi = tid / G_, g = tid % G_;
        vt[oi][g] = v[(ot * O_TILE + oi) * G_ + g];
    }

    // load s region with zero halo: 9*18*66 = 10692 elements
    const float* sb = s + (long)b * G_ * HW_;
    float* slf = &sl[0][0][0];
    for (int i = tid; i < G_ * SROWS * SCOLS; i += 256) {
        int g   = i / (SROWS * SCOLS);
        int rem = i - g * (SROWS * SCOLS);
        int r   = rem / SCOLS;
        int wc  = rem - r * SCOLS;
        int gh  = h0 - 1 + r;
        int gw  = wc - 1;
        float val = 0.0f;
        if ((unsigned)gh < (unsigned)H_ && (unsigned)gw < (unsigned)W_)
            val = sb[g * HW_ + gh * W_ + gw];
        slf[i] = val;
    }
    __syncthreads();

    const int w0 = (tid & 15) * 4;    // 16 float4-columns cover W=64
    const int hl = tid >> 4;          // 16 rows

    float4 acc[O_TILE];
#pragma unroll
    for (int oi = 0; oi < O_TILE; ++oi) acc[oi] = make_float4(0.f, 0.f, 0.f, 0.f);

#pragma unroll
    for (int g = 0; g < G_; ++g) {
        const int gi = g / 3, gj = g % 3;
        const float s0 = sl[g][hl + gi][w0 + gj + 0];
        const float s1 = sl[g][hl + gi][w0 + gj + 1];
        const float s2 = sl[g][hl + gi][w0 + gj + 2];
        const float s3 = sl[g][hl + gi][w0 + gj + 3];
#pragma unroll
        for (int oi = 0; oi < O_TILE; ++oi) {
            const float vv = vt[oi][g];
            acc[oi].x += vv * s0;
            acc[oi].y += vv * s1;
            acc[oi].z += vv * s2;
            acc[oi].w += vv * s3;
        }
    }

    // stores: threads 0..63 write 1 KiB contiguous (4 rows x 256 B)
    long obase = (((long)b * COUT + ot * O_TILE) * H_ + (h0 + hl)) * W_ + w0;
#pragma unroll
    for (int oi = 0; oi < O_TILE; ++oi) {
        *(float4*)(out + obase + (long)oi * HW_) = acc[oi];
    }
}

// ---------------------------------------------------------------------------
extern "C" void kernel_launch(void* const* d_in, const int* in_sizes, int n_in,
                              void* d_out, int out_size, void* d_ws, size_t ws_size,
                              hipStream_t stream) {
    const float* x    = (const float*)d_in[0];   // (32,256,64,64) fp32
    const float* w_pw = (const float*)d_in[1];   // (512,512) fp32
    float* out = (float*)d_out;                  // (32,512,64,64) fp32

    // workspace layout: v at 0 (18 KiB), s at 32 KiB (4.5 MiB)
    float* v = (float*)d_ws;
    float* s = (float*)((char*)d_ws + 32768);

    // A: w reduction -> v[512][9]
    reduce_w_kernel<<<COUT, 64, 0, stream>>>(w_pw, v);

    // B: x group sum -> s[32][9][64][64]
    {
        int total4 = B_ * G_ * HW4_;              // 294912 float4
        group_sum_kernel<<<total4 / 256, 256, 0, stream>>>(x, s);
    }

    // C: main shifted pointwise
    {
        int grid = B_ * (H_ / H_TILE) * (COUT / O_TILE);   // 32*4*32 = 4096
        shift_pw_kernel<<<grid, 256, 0, stream>>>(s, v, out);
    }
}

// Round 2
// 414.976 us; speedup vs baseline: 1.0841x; 1.0841x over previous
//
#include <hip/hip_runtime.h>

// Problem constants
#define B_   32
#define CIN  256
#define H_   64
#define W_   64
#define COUT 512
#define G_   9
#define CPG_IN  28          // 252 used input channels / 9 groups
#define HW_  (H_*W_)        // 4096
#define HW4_ (HW_/4)        // 1024 float4 per plane

typedef float f4 __attribute__((ext_vector_type(4)));

// ---------------------------------------------------------------------------
// Kernel A: v[o][g] = sum of w_pw[o, c] over group g's columns.
// g = c/56 for c < 504; c in [504,512) folds into centre group 4.
// One block (64 threads) per o; per-group wave shuffle reduction, no atomics.
// ---------------------------------------------------------------------------
__global__ __launch_bounds__(64) void reduce_w_kernel(const float* __restrict__ w,
                                                      float* __restrict__ v) {
    const int o = blockIdx.x;
    const int t = threadIdx.x;          // 0..63
    const float* row = w + o * COUT;
#pragma unroll
    for (int g = 0; g < G_; ++g) {
        float val = (t < 56) ? row[g * 56 + t] : 0.0f;
        if (g == 4 && t >= 56) val = row[504 + (t - 56)];   // miss channels -> centre
#pragma unroll
        for (int off = 32; off; off >>= 1) val += __shfl_down(val, off);
        if (t == 0) v[o * G_ + g] = val;
    }
}

// ---------------------------------------------------------------------------
// Kernel B: s[b][g][h][w] = sum_{k<28} x[b][28g+k][h][w]   (float4 along w)
// x is touch-once -> nontemporal loads; s must stay L2-resident -> normal store.
// ---------------------------------------------------------------------------
__global__ __launch_bounds__(256) void group_sum_kernel(const float* __restrict__ x,
                                                        float* __restrict__ s) {
    const int idx = blockIdx.x * 256 + threadIdx.x;   // float4 units; total B*9*1024
    const int hw = idx & (HW4_ - 1);
    const int gb = idx >> 10;          // b*9 + g
    const int g  = gb % G_;
    const int b  = gb / G_;
    const f4* xp = (const f4*)x;
    long base = ((long)(b * CIN + g * CPG_IN)) * HW4_ + hw;
    f4 acc = (f4)0.0f;
#pragma unroll
    for (int k = 0; k < CPG_IN; ++k) {
        acc += __builtin_nontemporal_load(xp + base + (long)k * HW4_);
    }
    ((f4*)s)[idx] = acc;
}

// ---------------------------------------------------------------------------
// Kernel C: out[b][o][h][w] = sum_g v[o][g] * s[b][g][h + g/3 - 1][w + g%3 - 1]
// Block: 256 threads -> tile of O_TILE=16 outputs x H_TILE=16 rows x 64 cols.
// s region staged in LDS [9][18][67]: row stride 67 (odd mod 32) -> 2 lanes/bank
// (free per m136); v read via block-uniform global loads (compiler -> s_load).
// out is touch-once -> nontemporal stores (keeps s slab in L2).
// ---------------------------------------------------------------------------
#define O_TILE 16
#define H_TILE 16
#define SROWS  (H_TILE + 2)   // 18
#define SCOLS  67             // 66 used + 1 pad (bank-conflict break)
#define SUSED  66

__global__ __launch_bounds__(256) void shift_pw_kernel(const float* __restrict__ s,
                                                       const float* __restrict__ v,
                                                       float* __restrict__ out) {
    __shared__ float sl[G_][SROWS][SCOLS];   // 9*18*67*4 = 43416 B -> 3 blocks/CU

    const int bid = blockIdx.x;
    const int ot  = bid & 31;         // 32 o-tiles
    const int ht  = (bid >> 5) & 3;   // 4 h-tiles
    const int b   = bid >> 7;         // 32 batches
    const int h0  = ht * H_TILE;
    const int tid = threadIdx.x;
    const int o0  = ot * O_TILE;

    // Stage s region with zero halo: per g, 18 rows x 66 cols (col 66 never read).
    const float* sb = s + (long)b * G_ * HW_;
#pragma unroll
    for (int g = 0; g < G_; ++g) {
        for (int i = tid; i < SROWS * SUSED; i += 256) {
            int r  = i / SUSED;
            int wc = i - r * SUSED;
            int gh = h0 - 1 + r;
            int gw = wc - 1;
            float val = 0.0f;
            if ((unsigned)gh < (unsigned)H_ && (unsigned)gw < (unsigned)W_)
                val = sb[g * HW_ + gh * W_ + gw];
            sl[g][r][wc] = val;
        }
    }
    __syncthreads();

    const int w0 = (tid & 15) * 4;    // 16 float4-columns cover W=64
    const int hl = tid >> 4;          // 16 rows

    f4 acc[O_TILE];
#pragma unroll
    for (int oi = 0; oi < O_TILE; ++oi) acc[oi] = (f4)0.0f;

#pragma unroll
    for (int g = 0; g < G_; ++g) {
        const int gi = g / 3, gj = g % 3;
        const float s0 = sl[g][hl + gi][w0 + gj + 0];
        const float s1 = sl[g][hl + gi][w0 + gj + 1];
        const float s2 = sl[g][hl + gi][w0 + gj + 2];
        const float s3 = sl[g][hl + gi][w0 + gj + 3];
#pragma unroll
        for (int oi = 0; oi < O_TILE; ++oi) {
            // block-uniform address -> scalar load, broadcast via SGPR operand
            const float vv = v[(o0 + oi) * G_ + g];
            acc[oi].x += vv * s0;
            acc[oi].y += vv * s1;
            acc[oi].z += vv * s2;
            acc[oi].w += vv * s3;
        }
    }

    // stores: each wave writes 4 full rows (1 KiB) contiguous per o-plane
    long obase = (((long)b * COUT + o0) * H_ + (h0 + hl)) * W_ + w0;
#pragma unroll
    for (int oi = 0; oi < O_TILE; ++oi) {
        __builtin_nontemporal_store(acc[oi], (f4*)(out + obase + (long)oi * HW_));
    }
}

// ---------------------------------------------------------------------------
extern "C" void kernel_launch(void* const* d_in, const int* in_sizes, int n_in,
                              void* d_out, int out_size, void* d_ws, size_t ws_size,
                              hipStream_t stream) {
    const float* x    = (const float*)d_in[0];   // (32,256,64,64) fp32
    const float* w_pw = (const float*)d_in[1];   // (512,512) fp32
    float* out = (float*)d_out;                  // (32,512,64,64) fp32

    // workspace layout: v at 0 (18 KiB), s at 32 KiB (4.5 MiB)
    float* v = (float*)d_ws;
    float* s = (float*)((char*)d_ws + 32768);

    // A: w reduction -> v[512][9]
    reduce_w_kernel<<<COUT, 64, 0, stream>>>(w_pw, v);

    // B: x group sum -> s[32][9][64][64]
    group_sum_kernel<<<(B_ * G_ * HW4_) / 256, 256, 0, stream>>>(x, s);

    // C: main shifted pointwise
    shift_pw_kernel<<<B_ * (H_ / H_TILE) * (COUT / O_TILE), 256, 0, stream>>>(s, v, out);
}